// Round 5
// baseline (85.225 us; speedup 1.0000x reference)
//
#include <hip/hip_runtime.h>

// Problem: logits = cls_embedding[N=50048,H=1024] @ W[1024] + b  (fp32),
// then per-segment double-softmax CE over S=1472 ragged segments (len<=64),
// mean over included segments. Output: logits[N] ++ loss[1].
//
// Structure (round 5):
//   K0: memsetAsync 16B (zero sum/cnt/done counter in ws)
//   K1: pure streaming matvec — 2048 blocks x 256 thr, grid-stride over row
//       pairs, 2 interleaved reduce chains, no LDS/barriers/segment logic.
//   K2: segment loss (wave per segment) + fence-free atomic accumulate +
//       last-block finalize (returned atomics ordered by the vmcnt(0) drain
//       that __syncthreads performs). NO __threadfence (round-3 post-mortem:
//       per-block L2-writeback fences cost ~45 us).

#define EACH_LEN 32   // length.shape[-1]

__device__ inline float wave_sum_f(float v) {
#pragma unroll
    for (int o = 32; o > 0; o >>= 1) v += __shfl_xor(v, o, 64);
    return v;
}
__device__ inline float wave_max_f(float v) {
#pragma unroll
    for (int o = 32; o > 0; o >>= 1) v = fmaxf(v, __shfl_xor(v, o, 64));
    return v;
}
__device__ inline int wave_sum_i(int v) {
#pragma unroll
    for (int o = 32; o > 0; o >>= 1) v += __shfl_xor(v, o, 64);
    return v;
}
__device__ inline int wave_max_i(int v) {
#pragma unroll
    for (int o = 32; o > 0; o >>= 1) v = max(v, __shfl_xor(v, o, 64));
    return v;
}

// K1: one wave handles row pairs (2p, 2p+1), grid-strided. Both reduce
// chains interleave; butterfly broadcast lets lane 0 store a float2.
__global__ __launch_bounds__(256) void matvec_kernel(
    const float* __restrict__ A, const float* __restrict__ W,
    const float* __restrict__ b, float* __restrict__ logits, int N) {
    const int wid  = threadIdx.x >> 6;
    const int lane = threadIdx.x & 63;
    const int gw   = blockIdx.x * 4 + wid;
    const int NW   = gridDim.x * 4;

    const float4* w4 = reinterpret_cast<const float4*>(W);
    float4 wv[4];
    wv[0] = w4[lane];       wv[1] = w4[lane + 64];
    wv[2] = w4[lane + 128]; wv[3] = w4[lane + 192];
    const float bias = b[0];

    const int NP = (N + 1) >> 1;
    for (int p = gw; p < NP; p += NW) {
        const int rowA = 2 * p;
        const int rowB = 2 * p + 1;
        const bool hasB = rowB < N;
        const float4* a4A = reinterpret_cast<const float4*>(A + (size_t)rowA * 1024);
        const float4* a4B = reinterpret_cast<const float4*>(A + (size_t)(hasB ? rowB : rowA) * 1024);
        float accA = 0.f, accB = 0.f;
#pragma unroll
        for (int k = 0; k < 4; ++k) {
            const float4 avA = a4A[lane + 64 * k];
            const float4 avB = a4B[lane + 64 * k];
            accA = fmaf(avA.x, wv[k].x, accA); accA = fmaf(avA.y, wv[k].y, accA);
            accA = fmaf(avA.z, wv[k].z, accA); accA = fmaf(avA.w, wv[k].w, accA);
            accB = fmaf(avB.x, wv[k].x, accB); accB = fmaf(avB.y, wv[k].y, accB);
            accB = fmaf(avB.z, wv[k].z, accB); accB = fmaf(avB.w, wv[k].w, accB);
        }
#pragma unroll
        for (int o = 32; o > 0; o >>= 1) {
            accA += __shfl_xor(accA, o, 64);
            accB += __shfl_xor(accB, o, 64);
        }
        if (lane == 0) {
            if (hasB) {
                float2 v2 = make_float2(accA + bias, accB + bias);
                *reinterpret_cast<float2*>(logits + rowA) = v2;   // rowA even -> aligned
            } else {
                logits[rowA] = accA + bias;
            }
        }
    }
}

// K2: wave per segment; double-softmax CE; fence-free atomic accumulate;
// last block writes the scalar loss.
// ws layout: acc[0]=sum(contrib), acc[1]=count(included), acc[2](as uint)=done
__global__ __launch_bounds__(256) void seg_loss_kernel(
    const float* __restrict__ logits, const int* __restrict__ lens,
    const int* __restrict__ tgt, float* __restrict__ acc,
    unsigned* __restrict__ done, float* __restrict__ loss, int S) {
    const int wid  = threadIdx.x >> 6;
    const int lane = threadIdx.x & 63;
    const int s    = blockIdx.x * 4 + wid;

    float o1 = 0.f, o2 = 0.f;
    if (s < S) {
        // offset = sum(lens[0..s))  (lens is tiny; L1/L2-resident)
        int part = 0;
        for (int j = lane; j < s; j += 64) part += lens[j];
        const int offset = wave_sum_i(part);
        const int len = lens[s];
        const bool valid = lane < len;

        const float l = valid ? logits[offset + lane] : -3.402823e38f;
        const float m = wave_max_f(l);
        const float e = valid ? __expf(l - m) : 0.f;
        const float Z = wave_sum_f(e);
        const float p = e / Z;

        const float q = valid ? __expf(p) : 0.f;
        const float lse2 = __logf(wave_sum_f(q));

        const int tv = valid ? tgt[offset + lane] : -1;
        const int maxt = wave_max_i(tv);
        const unsigned long long ball = __ballot(tv == maxt);
        const int t_idx = __ffsll(ball) - 1;
        const float p_t = __shfl(p, t_idx, 64);

        const int tgt_sum = wave_sum_i(valid ? tv : 0);

        const int next_len = (s + 1 < S) ? lens[s + 1] : 1;
        const bool skip_next_zero = (s > 0) && (s + 1 < S) && (next_len == 0);
        const bool skip_no_pos = (((s + 1) % EACH_LEN) == 0) && (tgt_sum <= 0);
        const bool include = (len > 0) && !skip_next_zero && !skip_no_pos;

        if (lane == 0) {
            // uniform, returned atomics (return forces completion before
            // the vmcnt(0) drain below)
            o1 = atomicAdd(&acc[0], include ? (lse2 - p_t) : 0.f);
            o2 = atomicAdd(&acc[1], include ? 1.f : 0.f);
        }
    }
    // keep the returns live so the adds aren't fire-and-forget
    if (o1 == -3.25e37f && o2 == -3.25e37f) acc[0] = 0.f;  // never true

    // __syncthreads drains vmcnt(0): all this block's atomics are complete
    // (acked at the coherence point) before the counter bump.
    __syncthreads();

    if (threadIdx.x == 0) {
        const unsigned old = atomicAdd(done, 1u);
        if (old == gridDim.x - 1) {
            const float Asum = atomicAdd(&acc[0], 0.f);   // coherent read
            const float Csum = atomicAdd(&acc[1], 0.f);
            loss[0] = Asum / (Csum > 0.f ? Csum : 1e-4f);
        }
    }
}

extern "C" void kernel_launch(void* const* d_in, const int* in_sizes, int n_in,
                              void* d_out, int out_size, void* d_ws, size_t ws_size,
                              hipStream_t stream) {
    const float* A   = (const float*)d_in[0];   // cls_embedding [N,H]
    const float* W   = (const float*)d_in[1];   // [H,1]
    const float* b   = (const float*)d_in[2];   // [1]
    const int*  lens = (const int*)d_in[3];     // [S]
    const int*  tgt  = (const int*)d_in[4];     // [N]

    const int H = in_sizes[1];                  // 1024
    const int N = in_sizes[0] / H;               // 50048
    const int S = in_sizes[3];                  // 1472

    float* logits = (float*)d_out;              // [N]
    float* loss   = logits + N;                 // [1]

    float*    acc  = (float*)d_ws;              // [0]=sum, [1]=cnt
    unsigned* done = (unsigned*)d_ws + 2;       // finish counter

    hipMemsetAsync(d_ws, 0, 16, stream);        // re-zero accumulators per call

    matvec_kernel<<<2048, 256, 0, stream>>>(A, W, b, logits, N);
    seg_loss_kernel<<<(S + 3) / 4, 256, 0, stream>>>(logits, lens, tgt,
                                                     acc, done, loss, S);
}

// Round 6
// 43.301 us; speedup vs baseline: 1.9682x; 1.9682x over previous
//
#include <hip/hip_runtime.h>

// Problem: logits = cls_embedding[N=50048,H=1024] @ W[1024] + b  (fp32),
// then per-segment double-softmax CE over S=1472 ragged segments (len<=64),
// mean over included segments. Output: logits[N] ++ loss[1].
//
// Structure (round 6) — poison-free (post-mortems r3/r5: hipMemsetAsync nodes
// and device-atomic finalize cost ~45 us/replay; NEVER use them here):
//   K1 matvec: 2048 blocks x 256, grid-stride over row pairs, 2 interleaved
//      reduce chains. Block 0 / wave 0 additionally wave-scans lens -> offsets
//      in d_ws (hidden among 8192 streaming waves).
//   K2 seg_loss: wave per segment, offset via one uniform load, writes
//      (contrib, incl) float2 to d_ws.
//   K3 reduce: 1 block, sums 1472 float2, writes loss.

#define EACH_LEN 32   // length.shape[-1]

__device__ inline float wave_sum_f(float v) {
#pragma unroll
    for (int o = 32; o > 0; o >>= 1) v += __shfl_xor(v, o, 64);
    return v;
}
__device__ inline float wave_max_f(float v) {
#pragma unroll
    for (int o = 32; o > 0; o >>= 1) v = fmaxf(v, __shfl_xor(v, o, 64));
    return v;
}
__device__ inline int wave_sum_i(int v) {
#pragma unroll
    for (int o = 32; o > 0; o >>= 1) v += __shfl_xor(v, o, 64);
    return v;
}
__device__ inline int wave_max_i(int v) {
#pragma unroll
    for (int o = 32; o > 0; o >>= 1) v = max(v, __shfl_xor(v, o, 64));
    return v;
}

// K1: one wave handles row pairs (2p, 2p+1), grid-strided; block 0 wave 0
// also computes exclusive prefix offsets of lens.
__global__ __launch_bounds__(256) void matvec_kernel(
    const float* __restrict__ A, const float* __restrict__ W,
    const float* __restrict__ b, const int* __restrict__ lens,
    float* __restrict__ logits, int* __restrict__ offsets, int N, int S) {
    const int wid  = threadIdx.x >> 6;
    const int lane = threadIdx.x & 63;

    if (blockIdx.x == 0 && wid == 0) {
        // exclusive scan of lens into offsets (64-wide blocked scan)
        int carry = 0;
        for (int base = 0; base < S; base += 64) {
            const int idx = base + lane;
            const int v = (idx < S) ? lens[idx] : 0;
            int sc = v;
#pragma unroll
            for (int o = 1; o < 64; o <<= 1) {
                const int t = __shfl_up(sc, o, 64);
                if (lane >= o) sc += t;
            }
            if (idx < S) offsets[idx] = carry + sc - v;
            carry += __shfl(sc, 63, 64);
        }
    }

    const int gw = blockIdx.x * 4 + wid;
    const int NW = gridDim.x * 4;

    const float4* w4 = reinterpret_cast<const float4*>(W);
    float4 wv[4];
    wv[0] = w4[lane];       wv[1] = w4[lane + 64];
    wv[2] = w4[lane + 128]; wv[3] = w4[lane + 192];
    const float bias = b[0];

    const int NP = (N + 1) >> 1;
    for (int p = gw; p < NP; p += NW) {
        const int rowA = 2 * p;
        const int rowB = 2 * p + 1;
        const bool hasB = rowB < N;
        const float4* a4A = reinterpret_cast<const float4*>(A + (size_t)rowA * 1024);
        const float4* a4B = reinterpret_cast<const float4*>(A + (size_t)(hasB ? rowB : rowA) * 1024);
        float accA = 0.f, accB = 0.f;
#pragma unroll
        for (int k = 0; k < 4; ++k) {
            const float4 avA = a4A[lane + 64 * k];
            const float4 avB = a4B[lane + 64 * k];
            accA = fmaf(avA.x, wv[k].x, accA); accA = fmaf(avA.y, wv[k].y, accA);
            accA = fmaf(avA.z, wv[k].z, accA); accA = fmaf(avA.w, wv[k].w, accA);
            accB = fmaf(avB.x, wv[k].x, accB); accB = fmaf(avB.y, wv[k].y, accB);
            accB = fmaf(avB.z, wv[k].z, accB); accB = fmaf(avB.w, wv[k].w, accB);
        }
#pragma unroll
        for (int o = 32; o > 0; o >>= 1) {
            accA += __shfl_xor(accA, o, 64);
            accB += __shfl_xor(accB, o, 64);
        }
        if (lane == 0) {
            if (hasB) {
                *reinterpret_cast<float2*>(logits + rowA) =
                    make_float2(accA + bias, accB + bias);   // rowA even -> aligned
            } else {
                logits[rowA] = accA + bias;
            }
        }
    }
}

// K2: wave per segment; double-softmax CE; writes (contrib, incl) float2.
__global__ __launch_bounds__(256) void seg_loss_kernel(
    const float* __restrict__ logits, const int* __restrict__ lens,
    const int* __restrict__ tgt, const int* __restrict__ offsets,
    float2* __restrict__ pairs, int S) {
    const int wid  = threadIdx.x >> 6;
    const int lane = threadIdx.x & 63;
    const int s    = blockIdx.x * 4 + wid;
    if (s >= S) return;

    const int offset = offsets[s];
    const int len = lens[s];
    const bool valid = lane < len;

    const float l = valid ? logits[offset + lane] : -3.402823e38f;
    const float m = wave_max_f(l);
    const float e = valid ? __expf(l - m) : 0.f;
    const float Z = wave_sum_f(e);
    const float p = e / Z;

    const float q = valid ? __expf(p) : 0.f;
    const float lse2 = __logf(wave_sum_f(q));

    const int tv = valid ? tgt[offset + lane] : -1;
    const int maxt = wave_max_i(tv);
    const unsigned long long ball = __ballot(tv == maxt);
    const int t_idx = __ffsll(ball) - 1;
    const float p_t = __shfl(p, t_idx, 64);

    const int tgt_sum = wave_sum_i(valid ? tv : 0);

    const int next_len = (s + 1 < S) ? lens[s + 1] : 1;
    const bool skip_next_zero = (s > 0) && (s + 1 < S) && (next_len == 0);
    const bool skip_no_pos = (((s + 1) % EACH_LEN) == 0) && (tgt_sum <= 0);
    const bool include = (len > 0) && !skip_next_zero && !skip_no_pos;

    if (lane == 0)
        pairs[s] = include ? make_float2(lse2 - p_t, 1.f) : make_float2(0.f, 0.f);
}

__global__ __launch_bounds__(256) void reduce_kernel(
    const float2* __restrict__ pairs, float* __restrict__ out_loss, int S) {
    float a = 0.f, c = 0.f;
    for (int i = threadIdx.x; i < S; i += 256) {
        const float2 v = pairs[i];
        a += v.x;
        c += v.y;
    }
    a = wave_sum_f(a);
    c = wave_sum_f(c);
    __shared__ float wa[4], wc[4];
    const int wid = threadIdx.x >> 6, lane = threadIdx.x & 63;
    if (lane == 0) { wa[wid] = a; wc[wid] = c; }
    __syncthreads();
    if (threadIdx.x == 0) {
        const float A = wa[0] + wa[1] + wa[2] + wa[3];
        const float C = wc[0] + wc[1] + wc[2] + wc[3];
        out_loss[0] = A / (C > 0.f ? C : 1e-4f);
    }
}

extern "C" void kernel_launch(void* const* d_in, const int* in_sizes, int n_in,
                              void* d_out, int out_size, void* d_ws, size_t ws_size,
                              hipStream_t stream) {
    const float* A   = (const float*)d_in[0];   // cls_embedding [N,H]
    const float* W   = (const float*)d_in[1];   // [H,1]
    const float* b   = (const float*)d_in[2];   // [1]
    const int*  lens = (const int*)d_in[3];     // [S]
    const int*  tgt  = (const int*)d_in[4];     // [N]

    const int H = in_sizes[1];                  // 1024
    const int N = in_sizes[0] / H;              // 50048
    const int S = in_sizes[3];                  // 1472

    float* logits = (float*)d_out;              // [N]
    float* loss   = logits + N;                 // [1]

    int*    offsets = (int*)d_ws;                                   // [S]
    float2* pairs   = (float2*)((char*)d_ws + ((S * 4 + 15) & ~15)); // [S]

    matvec_kernel<<<2048, 256, 0, stream>>>(A, W, b, lens, logits, offsets, N, S);
    seg_loss_kernel<<<(S + 3) / 4, 256, 0, stream>>>(logits, lens, tgt,
                                                     offsets, pairs, S);
    reduce_kernel<<<1, 256, 0, stream>>>(pairs, loss, S);
}